// Round 2
// 605.712 us; speedup vs baseline: 1.0475x; 1.0475x over previous
//
#include <hip/hip_runtime.h>
#include <hip/hip_bf16.h>

// ArmaCell: B=1024, K=256, UNITS=32, P=4, Q=4
// out[b, j*32+u] = sum_{i,p} inputs[b,i*4+p]*kernel[p,u,i,j]
//                + sum_{i,q} state[b,(i*32+u)*4+q]*rk[q,u,i,j]
// out_state[b,n,:] = { out[b,n], state[b,n,0..2] }
//
// bf16 MFMA path: per u, C(1024x256) = A(1024x2048) @ W_u(2048x256),
// W pre-transposed to Wt[u][j][k] bf16 (k-contiguous, B^T layout) in d_ws.
//
// R1 (resubmit after infra failure): latency-bound fix
//  (baseline: MfmaUtil 4%, VALUBusy 5%, HBM 9%, Occ 19%):
//  - 64x128 tile -> grid 1024 blocks -> 4 blocks/CU, 16 waves/CU
//  - double-buffered LDS + depth-1 reg prefetch (issue loads for t+1
//    before MFMA of t; vmcnt-wait + cvt + ds_write after), 1 barrier/iter

typedef __attribute__((ext_vector_type(8))) short bf16x8;
typedef __attribute__((ext_vector_type(4))) float f32x4;

__device__ inline unsigned short f2bf(float x) {
    unsigned int u = __float_as_uint(x);
    return (unsigned short)((u + 0x7fffu + ((u >> 16) & 1u)) >> 16);
}

__device__ inline void cvt_store4(unsigned short* dst, float4 v) {
    float2 ab; ab.x = v.x; ab.y = v.y;
    float2 cd; cd.x = v.z; cd.y = v.w;
    __hip_bfloat162 lo = __float22bfloat162_rn(ab);   // v_cvt_pk_bf16_f32
    __hip_bfloat162 hi = __float22bfloat162_rn(cd);
    union { __hip_bfloat162 h2[2]; uint2 u2; } pk;
    pk.h2[0] = lo; pk.h2[1] = hi;
    *(uint2*)dst = pk.u2;   // 8B aligned by construction
}

// ---------------- Pre-pass: Wt[u][j][k] bf16, k = (AR: i*4+p) | (MA: 1024 + i*4+q)
__global__ __launch_bounds__(256) void prep_w(
    const float* __restrict__ kern,    // (4,32,256,256) [p][u][i][j]
    const float* __restrict__ rkern,   // (4,32,256,256) [q][u][i][j]
    unsigned short* __restrict__ Wt)   // (32,256,2048)
{
    const int u  = blockIdx.x;
    const int j0 = blockIdx.y * 64;
    const int zz = blockIdx.z;         // 0..31
    const int mm = zz >> 4;            // 0=kern, 1=rkern
    const int it = zz & 15;            // i-tile (16 i's -> 64 k's)
    const float* src = mm ? rkern : kern;
    const int kout = mm * 1024 + it * 64;

    __shared__ unsigned short T[64 * 72];   // [j][kk], pitch 72

    // jq fast across lanes -> 4 lanes read 256B contiguous; pp wave-uniform
    const int t  = threadIdx.x;
    const int jq = t & 3;              // 0..3
    const int ii = (t >> 2) & 15;      // 0..15
    const int pp = t >> 6;             // 0..3 (wave-uniform)
    const int i  = it * 16 + ii;
    const int kk = ii * 4 + pp;        // 0..63
    const float* row = src + ((size_t)((pp * 32 + u) * 256 + i)) * 256 + j0 + jq * 16;
    #pragma unroll
    for (int s = 0; s < 4; ++s) {
        float4 v = *(const float4*)(row + s * 4);
        const int jb = jq * 16 + s * 4;
        T[(jb + 0) * 72 + kk] = f2bf(v.x);
        T[(jb + 1) * 72 + kk] = f2bf(v.y);
        T[(jb + 2) * 72 + kk] = f2bf(v.z);
        T[(jb + 3) * 72 + kk] = f2bf(v.w);
    }
    __syncthreads();
    const int j = t >> 2, q = t & 3;
    unsigned short* dst = Wt + ((size_t)(u * 256 + j0 + j)) * 2048 + kout + q * 16;
    uint4 a = *(uint4*)&T[j * 72 + q * 16];
    uint4 b = *(uint4*)&T[j * 72 + q * 16 + 8];
    *(uint4*)dst = a;
    *(uint4*)(dst + 8) = b;
}

// ---------------- MFMA GEMM: grid (16 m-blocks, 2 n-blocks, 32 u), 256 thr
// tile 64x128, BK=32, double-buffered LDS, depth-1 prefetch
#define PITCH 40   // bf16 pitch: 80B rows -> 2-way LDS conflicts only (free)

__global__ __launch_bounds__(256, 4) void arma_gemm_mfma(
    const float* __restrict__ inputs,          // (1024,1024) fp32
    const float* __restrict__ state,           // (1024,32768) fp32
    const unsigned short* __restrict__ Wt,     // (32,256,2048) bf16
    float* __restrict__ out)                   // (1024,8192)
{
    const int u  = blockIdx.z;
    const int b0 = blockIdx.x * 64;
    const int j0 = blockIdx.y * 128;
    const int t  = threadIdx.x;
    const int lane = t & 63;
    const int wn = (t >> 6) * 32;      // wave's n-offset: 4 waves x 32 cols
    const int fm = lane & 15;          // m (A) / n (B) within 16-tile
    const int kq = lane >> 4;          // k-quad: k = kq*8 + 0..7

    __shared__ unsigned short Asr[2][64 * PITCH];   // [buf][b_local][k] bf16
    __shared__ unsigned short Wsr[2][128 * PITCH];  // [buf][j_local][k] bf16

    const int arow = t & 63;           // A: 64 rows
    const int aseg = t >> 6;           // k-segment: 8 floats (aseg*8)
    const int wrow = t >> 1;           // W: 128 rows
    const int wseg = t & 1;            // 16 shorts (wseg*16)

    f32x4 acc[4][2];
    #pragma unroll
    for (int a = 0; a < 4; ++a)
        #pragma unroll
        for (int b = 0; b < 2; ++b)
            acc[a][b] = (f32x4)0.0f;

    const unsigned short* wsrc = Wt + ((size_t)(u * 256 + j0 + wrow)) * 2048 + wseg * 16;
    const float* in_row = inputs + (size_t)(b0 + arow) * 1024 + aseg * 8;
    const float* st_row = state + (size_t)(b0 + arow) * 32768 + (size_t)u * 4;

    float4 a0, a1;
    uint4 w0, w1;

    auto LOAD = [&](int kt) {
        if (kt < 1024) {                      // AR phase: A from inputs, k-contiguous
            const float* s = in_row + kt;
            a0 = *(const float4*)(s);
            a1 = *(const float4*)(s + 4);
        } else {                              // MA phase: A from state, k=i*4+q
            const int kk = kt - 1024 + aseg * 8;
            const float* s = st_row + (size_t)(kk >> 2) * 128;
            a0 = *(const float4*)(s);
            a1 = *(const float4*)(s + 128);
        }
        w0 = *(const uint4*)(wsrc + kt);
        w1 = *(const uint4*)(wsrc + kt + 8);
    };
    auto STORE = [&](int buf) {
        unsigned short* ad = &Asr[buf][arow * PITCH + aseg * 8];
        cvt_store4(ad + 0, a0);
        cvt_store4(ad + 4, a1);
        unsigned short* wd = &Wsr[buf][wrow * PITCH + wseg * 16];
        *(uint4*)wd = w0;
        *(uint4*)(wd + 8) = w1;
    };
    auto COMPUTE = [&](int buf) {
        bf16x8 af[4], bfr[2];
        #pragma unroll
        for (int mt = 0; mt < 4; ++mt)
            af[mt] = *(const bf16x8*)&Asr[buf][(mt * 16 + fm) * PITCH + kq * 8];
        #pragma unroll
        for (int nt = 0; nt < 2; ++nt)
            bfr[nt] = *(const bf16x8*)&Wsr[buf][(wn + nt * 16 + fm) * PITCH + kq * 8];
        #pragma unroll
        for (int mt = 0; mt < 4; ++mt)
            #pragma unroll
            for (int nt = 0; nt < 2; ++nt)
                acc[mt][nt] = __builtin_amdgcn_mfma_f32_16x16x32_bf16(
                    af[mt], bfr[nt], acc[mt][nt], 0, 0, 0);
    };

    // prologue
    LOAD(0);
    STORE(0);
    __syncthreads();

    int cur = 0;
    for (int kt = 0; kt < 2048 - 32; kt += 32) {
        LOAD(kt + 32);          // issue next tile's loads (vmcnt waits sink to STORE)
        COMPUTE(cur);           // ds_read + MFMA on current buffer hides latency
        STORE(cur ^ 1);         // wait loads, cvt, write other buffer
        __syncthreads();        // single barrier per iteration
        cur ^= 1;
    }
    COMPUTE(cur);               // epilogue iteration, no prefetch

    // Epilogue: C row=(kq*4+reg), col=fm; out[b, j*32+u] scattered 4B (L2 combines)
    #pragma unroll
    for (int mt = 0; mt < 4; ++mt) {
        const int rbase = b0 + mt * 16 + kq * 4;
        #pragma unroll
        for (int nt = 0; nt < 2; ++nt) {
            const int col = j0 + wn + nt * 16 + fm;
            float* op = out + (size_t)rbase * 8192 + (size_t)col * 32 + u;
            op[0]        = acc[mt][nt][0];
            op[8192]     = acc[mt][nt][1];
            op[2 * 8192] = acc[mt][nt][2];
            op[3 * 8192] = acc[mt][nt][3];
        }
    }
}

// ---------------- fp32 fallback GEMM (round-1 kernel, used only if ws too small)
#define BM 64
#define BN 64
#define BKF 16
#define LDP 68

__global__ __launch_bounds__(256) void arma_gemm_f32(
    const float* __restrict__ inputs, const float* __restrict__ state,
    const float* __restrict__ kern, const float* __restrict__ rkern,
    float* __restrict__ out)
{
    const int u = blockIdx.z, b0 = blockIdx.x * BM, j0 = blockIdx.y * BN;
    const int tid = threadIdx.x;
    __shared__ float As[BKF][LDP];
    __shared__ float Ws[BKF][LDP];
    const int tx = tid & 15, ty = tid >> 4;
    const int arow = tid >> 2, ak4 = (tid & 3) * 4;
    const int wrow = tid >> 4, wj = (tid & 15) * 4;
    float acc[4][4] = {{0.f}};
    for (int kt = 0; kt < 1024; kt += BKF) {
        const float4 av = *(const float4*)(inputs + (size_t)(b0 + arow) * 1024 + kt + ak4);
        As[ak4 + 0][arow] = av.x; As[ak4 + 1][arow] = av.y;
        As[ak4 + 2][arow] = av.z; As[ak4 + 3][arow] = av.w;
        const int ip = kt + wrow;
        const float4 wv = *(const float4*)(kern + ((size_t)(((ip & 3) * 32 + u) * 256 + (ip >> 2))) * 256 + j0 + wj);
        *(float4*)&Ws[wrow][wj] = wv;
        __syncthreads();
        #pragma unroll
        for (int kk = 0; kk < BKF; ++kk) {
            const float4 a4 = *(const float4*)&As[kk][ty * 4];
            const float4 w4 = *(const float4*)&Ws[kk][tx * 4];
            acc[0][0] += a4.x * w4.x; acc[0][1] += a4.x * w4.y; acc[0][2] += a4.x * w4.z; acc[0][3] += a4.x * w4.w;
            acc[1][0] += a4.y * w4.x; acc[1][1] += a4.y * w4.y; acc[1][2] += a4.y * w4.z; acc[1][3] += a4.y * w4.w;
            acc[2][0] += a4.z * w4.x; acc[2][1] += a4.z * w4.y; acc[2][2] += a4.z * w4.z; acc[2][3] += a4.z * w4.w;
            acc[3][0] += a4.w * w4.x; acc[3][1] += a4.w * w4.y; acc[3][2] += a4.w * w4.z; acc[3][3] += a4.w * w4.w;
        }
        __syncthreads();
    }
    for (int kt = 0; kt < 1024; kt += BKF) {
        const int i = (kt >> 2) + (tid & 3);
        const float4 av = *(const float4*)(state + (size_t)(b0 + arow) * 32768 + (size_t)(i * 32 + u) * 4);
        As[ak4 + 0][arow] = av.x; As[ak4 + 1][arow] = av.y;
        As[ak4 + 2][arow] = av.z; As[ak4 + 3][arow] = av.w;
        const int iq = kt + wrow;
        const float4 wv = *(const float4*)(rkern + ((size_t)(((iq & 3) * 32 + u) * 256 + (iq >> 2))) * 256 + j0 + wj);
        *(float4*)&Ws[wrow][wj] = wv;
        __syncthreads();
        #pragma unroll
        for (int kk = 0; kk < BKF; ++kk) {
            const float4 a4 = *(const float4*)&As[kk][ty * 4];
            const float4 w4 = *(const float4*)&Ws[kk][tx * 4];
            acc[0][0] += a4.x * w4.x; acc[0][1] += a4.x * w4.y; acc[0][2] += a4.x * w4.z; acc[0][3] += a4.x * w4.w;
            acc[1][0] += a4.y * w4.x; acc[1][1] += a4.y * w4.y; acc[1][2] += a4.y * w4.z; acc[1][3] += a4.y * w4.w;
            acc[2][0] += a4.z * w4.x; acc[2][1] += a4.z * w4.y; acc[2][2] += a4.z * w4.z; acc[2][3] += a4.z * w4.w;
            acc[3][0] += a4.w * w4.x; acc[3][1] += a4.w * w4.y; acc[3][2] += a4.w * w4.z; acc[3][3] += a4.w * w4.w;
        }
        __syncthreads();
    }
    const int bb = b0 + ty * 4, jj = j0 + tx * 4;
    #pragma unroll
    for (int r = 0; r < 4; ++r)
        #pragma unroll
        for (int c = 0; c < 4; ++c)
            out[(size_t)(bb + r) * 8192 + (size_t)(jj + c) * 32 + u] = acc[r][c];
}

// ---------------- Assemble: out_state[b,n,:] = { out[b,n], state[b,n,0..2] }
__global__ __launch_bounds__(256) void arma_assemble2(
    const float* __restrict__ state,
    const float* __restrict__ out,
    float* __restrict__ out_state)
{
    const size_t i = (size_t)blockIdx.x * 256 + threadIdx.x;  // 0 .. B*N/4-1
    const f32x4 o = *(const f32x4*)(out + i * 4);
    const float* sp = state + i * 16;
    const f32x4 s0 = *(const f32x4*)(sp + 0);
    const f32x4 s1 = *(const f32x4*)(sp + 4);
    const f32x4 s2 = *(const f32x4*)(sp + 8);
    const f32x4 s3 = *(const f32x4*)(sp + 12);
    f32x4 r0 = { o[0], s0[0], s0[1], s0[2] };
    f32x4 r1 = { o[1], s1[0], s1[1], s1[2] };
    f32x4 r2 = { o[2], s2[0], s2[1], s2[2] };
    f32x4 r3 = { o[3], s3[0], s3[1], s3[2] };
    f32x4* dp = (f32x4*)(out_state + i * 16);
    __builtin_nontemporal_store(r0, dp + 0);
    __builtin_nontemporal_store(r1, dp + 1);
    __builtin_nontemporal_store(r2, dp + 2);
    __builtin_nontemporal_store(r3, dp + 3);
}

extern "C" void kernel_launch(void* const* d_in, const int* in_sizes, int n_in,
                              void* d_out, int out_size, void* d_ws, size_t ws_size,
                              hipStream_t stream) {
    const float* inputs = (const float*)d_in[0];
    const float* state  = (const float*)d_in[1];
    const float* kern   = (const float*)d_in[2];
    const float* rkern  = (const float*)d_in[3];

    float* out       = (float*)d_out;
    float* out_state = (float*)d_out + 8388608;

    const size_t WT_BYTES = (size_t)32 * 256 * 2048 * 2;  // 33.5 MB

    if (ws_size >= WT_BYTES) {
        unsigned short* Wt = (unsigned short*)d_ws;
        prep_w<<<dim3(32, 4, 32), 256, 0, stream>>>(kern, rkern, Wt);
        arma_gemm_mfma<<<dim3(16, 2, 32), 256, 0, stream>>>(inputs, state, Wt, out);
    } else {
        arma_gemm_f32<<<dim3(16, 4, 32), 256, 0, stream>>>(inputs, state, kern, rkern, out);
    }
    arma_assemble2<<<8388608 / 4 / 256, 256, 0, stream>>>(state, out, out_state);
}

// Round 3
// 532.063 us; speedup vs baseline: 1.1925x; 1.1384x over previous
//
#include <hip/hip_runtime.h>
#include <hip/hip_bf16.h>

// ArmaCell: B=1024, K=256, UNITS=32, P=4, Q=4
// out[b, j*32+u] = sum_{i,p} inputs[b,i*4+p]*kernel[p,u,i,j]
//                + sum_{i,q} state[b,(i*32+u)*4+q]*rk[q,u,i,j]
// out_state[b,n,:] = { out[b,n], state[b,n,0..2] }
//
// R2: transaction-bound fix. R1 showed 2x occupancy -> only 1.1x speedup with
// all pipes <10% busy: the global loads were 64-transactions-per-instruction
// (4KB/128KB lane strides). New path: streaming pre-passes pack A (inputs+state
// -> bf16, per-iteration-contiguous tiles, per-u for the MA half) and W into
// tile-contiguous layouts; GEMM inner-loop loads become fully coalesced.
// Needs 103MB workspace; falls back to R1 path (33.5MB) else fp32 path.

typedef __attribute__((ext_vector_type(8))) short bf16x8;
typedef __attribute__((ext_vector_type(4))) float f32x4;

__device__ inline unsigned short f2bf(float x) {
    unsigned int u = __float_as_uint(x);
    return (unsigned short)((u + 0x7fffu + ((u >> 16) & 1u)) >> 16);
}

__device__ inline void cvt_store4(unsigned short* dst, float4 v) {
    float2 ab; ab.x = v.x; ab.y = v.y;
    float2 cd; cd.x = v.z; cd.y = v.w;
    __hip_bfloat162 lo = __float22bfloat162_rn(ab);   // v_cvt_pk_bf16_f32
    __hip_bfloat162 hi = __float22bfloat162_rn(cd);
    union { __hip_bfloat162 h2[2]; uint2 u2; } pk;
    pk.h2[0] = lo; pk.h2[1] = hi;
    *(uint2*)dst = pk.u2;   // 8B aligned by construction
}

__device__ inline void cvt_store2(unsigned short* dst, float4 v) {
    // store v.x..v.w as 4 bf16 (8B)
    float2 ab; ab.x = v.x; ab.y = v.y;
    float2 cd; cd.x = v.z; cd.y = v.w;
    __hip_bfloat162 lo = __float22bfloat162_rn(ab);
    __hip_bfloat162 hi = __float22bfloat162_rn(cd);
    union { __hip_bfloat162 h2[2]; uint2 u2; } pk;
    pk.h2[0] = lo; pk.h2[1] = hi;
    *(uint2*)dst = pk.u2;
}

// ================= NEW PATH (R2) ====================================
// Workspace layout (bytes):
//   Wtt  : [32 u][2 jb][64 kt][128 j][32 k] bf16   = 33,554,432
//   At_ar: [16 mb][32 kt][64 b][32 k] bf16         =  2,097,152   (k 0..1023)
//   At_ma: [32 u][16 mb][32 kt][64 b][32 k] bf16   = 67,108,864   (k 1024..2047)
// total 102,760,448

// ---- prep_w2: Wtt[u][jb][kt][j][kk] = Wt[u][j][kt*32+kk]
__global__ __launch_bounds__(256) void prep_w2(
    const float* __restrict__ kern,    // (4,32,256,256) [p][u][i][j]
    const float* __restrict__ rkern,   // (4,32,256,256) [q][u][i][j]
    unsigned short* __restrict__ Wtt)  // (32,2,64,128,32)
{
    const int u  = blockIdx.x;
    const int j0 = blockIdx.y * 64;
    const int zz = blockIdx.z;         // 0..31
    const int mm = zz >> 4;            // 0=kern, 1=rkern
    const int it = zz & 15;            // i-tile (16 i's -> 64 k's)
    const float* src = mm ? rkern : kern;
    const int kout = mm * 1024 + it * 64;

    __shared__ unsigned short T[64 * 72];   // [j][kk], pitch 72

    const int t  = threadIdx.x;
    const int jq = t & 3;
    const int ii = (t >> 2) & 15;
    const int pp = t >> 6;             // wave-uniform
    const int i  = it * 16 + ii;
    const int kk = ii * 4 + pp;        // 0..63
    const float* row = src + ((size_t)((pp * 32 + u) * 256 + i)) * 256 + j0 + jq * 16;
    #pragma unroll
    for (int s = 0; s < 4; ++s) {
        float4 v = *(const float4*)(row + s * 4);
        const int jb_ = jq * 16 + s * 4;
        T[(jb_ + 0) * 72 + kk] = f2bf(v.x);
        T[(jb_ + 1) * 72 + kk] = f2bf(v.y);
        T[(jb_ + 2) * 72 + kk] = f2bf(v.z);
        T[(jb_ + 3) * 72 + kk] = f2bf(v.w);
    }
    __syncthreads();
    const int j = t >> 2, q = t & 3;
    const int kglob = kout + q * 16;             // 16-short run, 32-aligned tiles
    const int kt  = kglob >> 5;                  // 0..63
    const int kk0 = kglob & 31;                  // 0 or 16
    const int jb  = blockIdx.y >> 1;
    const int jloc = (blockIdx.y & 1) * 64 + j;
    unsigned short* dst = Wtt +
        ((((size_t)(u * 2 + jb) * 64 + kt) * 128 + jloc) * 32 + kk0);
    uint4 a = *(uint4*)&T[j * 72 + q * 16];
    uint4 b = *(uint4*)&T[j * 72 + q * 16 + 8];
    *(uint4*)dst = a;
    *(uint4*)(dst + 8) = b;
}

// ---- prep_a: stream inputs+state (coalesced reads) -> tiled bf16 A
// blocks [0,512): AR part; blocks [512, 512+32768): MA part
__global__ __launch_bounds__(256) void prep_a(
    const float* __restrict__ inputs,   // (1024,1024)
    const float* __restrict__ state,    // (1024,32768)
    unsigned short* __restrict__ At_ar, // (16,32,64,32)
    unsigned short* __restrict__ At_ma) // (32,16,32,64,32)
{
    const int bid = blockIdx.x;
    if (bid < 512) {
        // 8 floats/thread, fully coalesced read of inputs
        const size_t e = ((size_t)bid * 256 + threadIdx.x) * 8;
        const int b = (int)(e >> 10), k = (int)(e & 1023);
        float4 v0 = *(const float4*)(inputs + e);
        float4 v1 = *(const float4*)(inputs + e + 4);
        const int mb = b >> 6, row = b & 63, kt = k >> 5, kk = k & 31;
        unsigned short* d = At_ar + (((size_t)(mb * 32 + kt) * 64 + row) * 32 + kk);
        cvt_store4(d, v0);
        cvt_store4(d + 4, v1);
    } else {
        // 1 float4/thread, fully coalesced read of state
        const size_t e4 = (size_t)(bid - 512) * 256 + threadIdx.x;
        const int b = (int)(e4 >> 13), col4 = (int)(e4 & 8191);
        const int i = col4 >> 5, u = col4 & 31;      // col = i*128 + u*4 + q
        float4 v = *(const float4*)(state + e4 * 4);
        const int mb = b >> 6, row = b & 63;
        const int ktp = i >> 3;                      // (i*4)>>5
        const int kk = (i * 4) & 31;                 // + q contiguous
        unsigned short* d = At_ma +
            ((((size_t)(u * 16 + mb) * 32 + ktp) * 64 + row) * 32 + kk);
        cvt_store2(d, v);                            // 4 bf16, 8B
    }
}

// ---- GEMM v2: grid (16 mb, 2 jb, 32 u), 256 thr, 64x128 tile, BK=32
#define PITCH 40   // bf16 pitch: 80B rows -> 2-way LDS aliasing only (free)

__global__ __launch_bounds__(256, 4) void arma_gemm_mfma2(
    const unsigned short* __restrict__ At_ar,   // (16,32,64,32) bf16
    const unsigned short* __restrict__ At_ma,   // (32,16,32,64,32) bf16
    const unsigned short* __restrict__ Wtt,     // (32,2,64,128,32) bf16
    float* __restrict__ out)                    // (1024,8192)
{
    const int u  = blockIdx.z;
    const int mb = blockIdx.x;
    const int jb = blockIdx.y;
    const int b0 = mb * 64;
    const int j0 = jb * 128;
    const int t  = threadIdx.x;
    const int lane = t & 63;
    const int wn = (t >> 6) * 32;      // wave's n-offset: 4 waves x 32 cols
    const int fm = lane & 15;
    const int kq = lane >> 4;

    __shared__ unsigned short Asr[2][64 * PITCH];
    __shared__ unsigned short Wsr[2][128 * PITCH];

    // staging maps (tiles are contiguous):
    // A: 4KB tile, thread t -> 16B at t*8 elems  => row=t>>2, off=(t&3)*8
    // W: 8KB tile, thread t -> 32B at t*16 elems => row=t>>1, off=(t&1)*16
    const int ar_row = t >> 2, ar_off = (t & 3) * 8;
    const int w_row  = t >> 1, w_off  = (t & 1) * 16;

    f32x4 acc[4][2];
    #pragma unroll
    for (int a = 0; a < 4; ++a)
        #pragma unroll
        for (int b = 0; b < 2; ++b)
            acc[a][b] = (f32x4)0.0f;

    const unsigned short* abase_ar = At_ar + (size_t)mb * 32 * 2048 + t * 8;
    const unsigned short* abase_ma = At_ma + (size_t)(u * 16 + mb) * 32 * 2048 + t * 8;
    const unsigned short* wbase    = Wtt + (size_t)(u * 2 + jb) * 64 * 4096 + t * 16;

    uint4 av, w0, w1;

    auto LOAD = [&](int kt) {
        const unsigned short* ta = (kt < 32) ? (abase_ar + (size_t)kt * 2048)
                                             : (abase_ma + (size_t)(kt - 32) * 2048);
        av = *(const uint4*)ta;
        const unsigned short* tw = wbase + (size_t)kt * 4096;
        w0 = *(const uint4*)tw;
        w1 = *(const uint4*)(tw + 2048);   // second 16B: t*16+8 elems? no:
        // NOTE: thread covers elems [t*16, t*16+16). First uint4 = 8 elems at
        // t*16, second at t*16+8. tw points at elem t*16; +8 elems = +8 shorts.
    };
    auto LOADW_FIX = [&](int kt) {
        const unsigned short* tw = wbase + (size_t)kt * 4096;
        w0 = *(const uint4*)tw;
        w1 = *(const uint4*)(tw + 8);
    };
    auto STORE = [&](int buf) {
        *(uint4*)&Asr[buf][ar_row * PITCH + ar_off] = av;
        unsigned short* wd = &Wsr[buf][w_row * PITCH + w_off];
        *(uint4*)wd = w0;
        *(uint4*)(wd + 8) = w1;
    };
    auto COMPUTE = [&](int buf) {
        bf16x8 af[4], bfr[2];
        #pragma unroll
        for (int mt = 0; mt < 4; ++mt)
            af[mt] = *(const bf16x8*)&Asr[buf][(mt * 16 + fm) * PITCH + kq * 8];
        #pragma unroll
        for (int nt = 0; nt < 2; ++nt)
            bfr[nt] = *(const bf16x8*)&Wsr[buf][(wn + nt * 16 + fm) * PITCH + kq * 8];
        #pragma unroll
        for (int mt = 0; mt < 4; ++mt)
            #pragma unroll
            for (int nt = 0; nt < 2; ++nt)
                acc[mt][nt] = __builtin_amdgcn_mfma_f32_16x16x32_bf16(
                    af[mt], bfr[nt], acc[mt][nt], 0, 0, 0);
    };

    // prologue
    {
        const unsigned short* ta = abase_ar;
        av = *(const uint4*)ta;
        LOADW_FIX(0);
    }
    STORE(0);
    __syncthreads();

    int cur = 0;
    for (int kt = 0; kt < 63; ++kt) {
        // issue next tile's loads
        const int kn = kt + 1;
        const unsigned short* ta = (kn < 32) ? (abase_ar + (size_t)kn * 2048)
                                             : (abase_ma + (size_t)(kn - 32) * 2048);
        av = *(const uint4*)ta;
        LOADW_FIX(kn);
        COMPUTE(cur);
        STORE(cur ^ 1);
        __syncthreads();
        cur ^= 1;
    }
    COMPUTE(cur);

    // Epilogue: C row=(kq*4+reg), col=fm; out[b, j*32+u]
    #pragma unroll
    for (int mt = 0; mt < 4; ++mt) {
        const int rbase = b0 + mt * 16 + kq * 4;
        #pragma unroll
        for (int nt = 0; nt < 2; ++nt) {
            const int col = j0 + wn + nt * 16 + fm;
            float* op = out + (size_t)rbase * 8192 + (size_t)col * 32 + u;
            op[0]        = acc[mt][nt][0];
            op[8192]     = acc[mt][nt][1];
            op[2 * 8192] = acc[mt][nt][2];
            op[3 * 8192] = acc[mt][nt][3];
        }
    }
}

// ================= R1 PATH (fallback, 33.5MB ws) =====================
__global__ __launch_bounds__(256) void prep_w(
    const float* __restrict__ kern,
    const float* __restrict__ rkern,
    unsigned short* __restrict__ Wt)   // (32,256,2048)
{
    const int u  = blockIdx.x;
    const int j0 = blockIdx.y * 64;
    const int zz = blockIdx.z;
    const int mm = zz >> 4;
    const int it = zz & 15;
    const float* src = mm ? rkern : kern;
    const int kout = mm * 1024 + it * 64;

    __shared__ unsigned short T[64 * 72];

    const int t  = threadIdx.x;
    const int jq = t & 3;
    const int ii = (t >> 2) & 15;
    const int pp = t >> 6;
    const int i  = it * 16 + ii;
    const int kk = ii * 4 + pp;
    const float* row = src + ((size_t)((pp * 32 + u) * 256 + i)) * 256 + j0 + jq * 16;
    #pragma unroll
    for (int s = 0; s < 4; ++s) {
        float4 v = *(const float4*)(row + s * 4);
        const int jb = jq * 16 + s * 4;
        T[(jb + 0) * 72 + kk] = f2bf(v.x);
        T[(jb + 1) * 72 + kk] = f2bf(v.y);
        T[(jb + 2) * 72 + kk] = f2bf(v.z);
        T[(jb + 3) * 72 + kk] = f2bf(v.w);
    }
    __syncthreads();
    const int j = t >> 2, q = t & 3;
    unsigned short* dst = Wt + ((size_t)(u * 256 + j0 + j)) * 2048 + kout + q * 16;
    uint4 a = *(uint4*)&T[j * 72 + q * 16];
    uint4 b = *(uint4*)&T[j * 72 + q * 16 + 8];
    *(uint4*)dst = a;
    *(uint4*)(dst + 8) = b;
}

__global__ __launch_bounds__(256, 4) void arma_gemm_mfma(
    const float* __restrict__ inputs,
    const float* __restrict__ state,
    const unsigned short* __restrict__ Wt,
    float* __restrict__ out)
{
    const int u  = blockIdx.z;
    const int b0 = blockIdx.x * 64;
    const int j0 = blockIdx.y * 128;
    const int t  = threadIdx.x;
    const int lane = t & 63;
    const int wn = (t >> 6) * 32;
    const int fm = lane & 15;
    const int kq = lane >> 4;

    __shared__ unsigned short Asr[2][64 * PITCH];
    __shared__ unsigned short Wsr[2][128 * PITCH];

    const int arow = t & 63;
    const int aseg = t >> 6;
    const int wrow = t >> 1;
    const int wseg = t & 1;

    f32x4 acc[4][2];
    #pragma unroll
    for (int a = 0; a < 4; ++a)
        #pragma unroll
        for (int b = 0; b < 2; ++b)
            acc[a][b] = (f32x4)0.0f;

    const unsigned short* wsrc = Wt + ((size_t)(u * 256 + j0 + wrow)) * 2048 + wseg * 16;
    const float* in_row = inputs + (size_t)(b0 + arow) * 1024 + aseg * 8;
    const float* st_row = state + (size_t)(b0 + arow) * 32768 + (size_t)u * 4;

    float4 a0, a1;
    uint4 w0, w1;

    auto LOAD = [&](int kt) {
        if (kt < 1024) {
            const float* s = in_row + kt;
            a0 = *(const float4*)(s);
            a1 = *(const float4*)(s + 4);
        } else {
            const int kk = kt - 1024 + aseg * 8;
            const float* s = st_row + (size_t)(kk >> 2) * 128;
            a0 = *(const float4*)(s);
            a1 = *(const float4*)(s + 128);
        }
        w0 = *(const uint4*)(wsrc + kt);
        w1 = *(const uint4*)(wsrc + kt + 8);
    };
    auto STORE = [&](int buf) {
        unsigned short* ad = &Asr[buf][arow * PITCH + aseg * 8];
        cvt_store4(ad + 0, a0);
        cvt_store4(ad + 4, a1);
        unsigned short* wd = &Wsr[buf][wrow * PITCH + wseg * 16];
        *(uint4*)wd = w0;
        *(uint4*)(wd + 8) = w1;
    };
    auto COMPUTE = [&](int buf) {
        bf16x8 af[4], bfr[2];
        #pragma unroll
        for (int mt = 0; mt < 4; ++mt)
            af[mt] = *(const bf16x8*)&Asr[buf][(mt * 16 + fm) * PITCH + kq * 8];
        #pragma unroll
        for (int nt = 0; nt < 2; ++nt)
            bfr[nt] = *(const bf16x8*)&Wsr[buf][(wn + nt * 16 + fm) * PITCH + kq * 8];
        #pragma unroll
        for (int mt = 0; mt < 4; ++mt)
            #pragma unroll
            for (int nt = 0; nt < 2; ++nt)
                acc[mt][nt] = __builtin_amdgcn_mfma_f32_16x16x32_bf16(
                    af[mt], bfr[nt], acc[mt][nt], 0, 0, 0);
    };

    LOAD(0);
    STORE(0);
    __syncthreads();

    int cur = 0;
    for (int kt = 0; kt < 2048 - 32; kt += 32) {
        LOAD(kt + 32);
        COMPUTE(cur);
        STORE(cur ^ 1);
        __syncthreads();
        cur ^= 1;
    }
    COMPUTE(cur);

    #pragma unroll
    for (int mt = 0; mt < 4; ++mt) {
        const int rbase = b0 + mt * 16 + kq * 4;
        #pragma unroll
        for (int nt = 0; nt < 2; ++nt) {
            const int col = j0 + wn + nt * 16 + fm;
            float* op = out + (size_t)rbase * 8192 + (size_t)col * 32 + u;
            op[0]        = acc[mt][nt][0];
            op[8192]     = acc[mt][nt][1];
            op[2 * 8192] = acc[mt][nt][2];
            op[3 * 8192] = acc[mt][nt][3];
        }
    }
}

// ---------------- fp32 fallback GEMM
#define BM 64
#define BN 64
#define BKF 16
#define LDP 68

__global__ __launch_bounds__(256) void arma_gemm_f32(
    const float* __restrict__ inputs, const float* __restrict__ state,
    const float* __restrict__ kern, const float* __restrict__ rkern,
    float* __restrict__ out)
{
    const int u = blockIdx.z, b0 = blockIdx.x * BM, j0 = blockIdx.y * BN;
    const int tid = threadIdx.x;
    __shared__ float As[BKF][LDP];
    __shared__ float Ws[BKF][LDP];
    const int tx = tid & 15, ty = tid >> 4;
    const int arow = tid >> 2, ak4 = (tid & 3) * 4;
    const int wrow = tid >> 4, wj = (tid & 15) * 4;
    float acc[4][4] = {{0.f}};
    for (int kt = 0; kt < 1024; kt += BKF) {
        const float4 av = *(const float4*)(inputs + (size_t)(b0 + arow) * 1024 + kt + ak4);
        As[ak4 + 0][arow] = av.x; As[ak4 + 1][arow] = av.y;
        As[ak4 + 2][arow] = av.z; As[ak4 + 3][arow] = av.w;
        const int ip = kt + wrow;
        const float4 wv = *(const float4*)(kern + ((size_t)(((ip & 3) * 32 + u) * 256 + (ip >> 2))) * 256 + j0 + wj);
        *(float4*)&Ws[wrow][wj] = wv;
        __syncthreads();
        #pragma unroll
        for (int kk = 0; kk < BKF; ++kk) {
            const float4 a4 = *(const float4*)&As[kk][ty * 4];
            const float4 w4 = *(const float4*)&Ws[kk][tx * 4];
            acc[0][0] += a4.x * w4.x; acc[0][1] += a4.x * w4.y; acc[0][2] += a4.x * w4.z; acc[0][3] += a4.x * w4.w;
            acc[1][0] += a4.y * w4.x; acc[1][1] += a4.y * w4.y; acc[1][2] += a4.y * w4.z; acc[1][3] += a4.y * w4.w;
            acc[2][0] += a4.z * w4.x; acc[2][1] += a4.z * w4.y; acc[2][2] += a4.z * w4.z; acc[2][3] += a4.z * w4.w;
            acc[3][0] += a4.w * w4.x; acc[3][1] += a4.w * w4.y; acc[3][2] += a4.w * w4.z; acc[3][3] += a4.w * w4.w;
        }
        __syncthreads();
    }
    for (int kt = 0; kt < 1024; kt += BKF) {
        const int i = (kt >> 2) + (tid & 3);
        const float4 av = *(const float4*)(state + (size_t)(b0 + arow) * 32768 + (size_t)(i * 32 + u) * 4);
        As[ak4 + 0][arow] = av.x; As[ak4 + 1][arow] = av.y;
        As[ak4 + 2][arow] = av.z; As[ak4 + 3][arow] = av.w;
        const int iq = kt + wrow;
        const float4 wv = *(const float4*)(rkern + ((size_t)(((iq & 3) * 32 + u) * 256 + (iq >> 2))) * 256 + j0 + wj);
        *(float4*)&Ws[wrow][wj] = wv;
        __syncthreads();
        #pragma unroll
        for (int kk = 0; kk < BKF; ++kk) {
            const float4 a4 = *(const float4*)&As[kk][ty * 4];
            const float4 w4 = *(const float4*)&Ws[kk][tx * 4];
            acc[0][0] += a4.x * w4.x; acc[0][1] += a4.x * w4.y; acc[0][2] += a4.x * w4.z; acc[0][3] += a4.x * w4.w;
            acc[1][0] += a4.y * w4.x; acc[1][1] += a4.y * w4.y; acc[1][2] += a4.y * w4.z; acc[1][3] += a4.y * w4.w;
            acc[2][0] += a4.z * w4.x; acc[2][1] += a4.z * w4.y; acc[2][2] += a4.z * w4.z; acc[2][3] += a4.z * w4.w;
            acc[3][0] += a4.w * w4.x; acc[3][1] += a4.w * w4.y; acc[3][2] += a4.w * w4.z; acc[3][3] += a4.w * w4.w;
        }
        __syncthreads();
    }
    const int bb = b0 + ty * 4, jj = j0 + tx * 4;
    #pragma unroll
    for (int r = 0; r < 4; ++r)
        #pragma unroll
        for (int c = 0; c < 4; ++c)
            out[(size_t)(bb + r) * 8192 + (size_t)(jj + c) * 32 + u] = acc[r][c];
}

// ---------------- Assemble: out_state[b,n,:] = { out[b,n], state[b,n,0..2] }
__global__ __launch_bounds__(256) void arma_assemble2(
    const float* __restrict__ state,
    const float* __restrict__ out,
    float* __restrict__ out_state)
{
    const size_t i = (size_t)blockIdx.x * 256 + threadIdx.x;
    const f32x4 o = *(const f32x4*)(out + i * 4);
    const float* sp = state + i * 16;
    const f32x4 s0 = *(const f32x4*)(sp + 0);
    const f32x4 s1 = *(const f32x4*)(sp + 4);
    const f32x4 s2 = *(const f32x4*)(sp + 8);
    const f32x4 s3 = *(const f32x4*)(sp + 12);
    f32x4 r0 = { o[0], s0[0], s0[1], s0[2] };
    f32x4 r1 = { o[1], s1[0], s1[1], s1[2] };
    f32x4 r2 = { o[2], s2[0], s2[1], s2[2] };
    f32x4 r3 = { o[3], s3[0], s3[1], s3[2] };
    f32x4* dp = (f32x4*)(out_state + i * 16);
    __builtin_nontemporal_store(r0, dp + 0);
    __builtin_nontemporal_store(r1, dp + 1);
    __builtin_nontemporal_store(r2, dp + 2);
    __builtin_nontemporal_store(r3, dp + 3);
}

extern "C" void kernel_launch(void* const* d_in, const int* in_sizes, int n_in,
                              void* d_out, int out_size, void* d_ws, size_t ws_size,
                              hipStream_t stream) {
    const float* inputs = (const float*)d_in[0];
    const float* state  = (const float*)d_in[1];
    const float* kern   = (const float*)d_in[2];
    const float* rkern  = (const float*)d_in[3];

    float* out       = (float*)d_out;
    float* out_state = (float*)d_out + 8388608;

    const size_t WTT_BYTES  = (size_t)32 * 2 * 64 * 128 * 32 * 2;      // 33,554,432
    const size_t ATAR_BYTES = (size_t)16 * 32 * 64 * 32 * 2;           //  2,097,152
    const size_t ATMA_BYTES = (size_t)32 * 16 * 32 * 64 * 32 * 2;      // 67,108,864
    const size_t NEW_BYTES  = WTT_BYTES + ATAR_BYTES + ATMA_BYTES;     // 102,760,448
    const size_t WT_BYTES   = (size_t)32 * 256 * 2048 * 2;             // 33,554,432

    if (ws_size >= NEW_BYTES) {
        unsigned short* Wtt   = (unsigned short*)d_ws;
        unsigned short* At_ar = (unsigned short*)((char*)d_ws + WTT_BYTES);
        unsigned short* At_ma = (unsigned short*)((char*)d_ws + WTT_BYTES + ATAR_BYTES);
        prep_w2<<<dim3(32, 4, 32), 256, 0, stream>>>(kern, rkern, Wtt);
        prep_a<<<dim3(512 + 32768, 1, 1), 256, 0, stream>>>(inputs, state, At_ar, At_ma);
        arma_gemm_mfma2<<<dim3(16, 2, 32), 256, 0, stream>>>(At_ar, At_ma, Wtt, out);
    } else if (ws_size >= WT_BYTES) {
        unsigned short* Wt = (unsigned short*)d_ws;
        prep_w<<<dim3(32, 4, 32), 256, 0, stream>>>(kern, rkern, Wt);
        arma_gemm_mfma<<<dim3(16, 2, 32), 256, 0, stream>>>(inputs, state, Wt, out);
    } else {
        arma_gemm_f32<<<dim3(16, 4, 32), 256, 0, stream>>>(inputs, state, kern, rkern, out);
    }
    arma_assemble2<<<8388608 / 4 / 256, 256, 0, stream>>>(state, out, out_state);
}

// Round 5
// 440.420 us; speedup vs baseline: 1.4407x; 1.2081x over previous
//
#include <hip/hip_runtime.h>
#include <hip/hip_bf16.h>

// ArmaCell: B=1024, K=256, UNITS=32, P=4, Q=4
// out[b, j*32+u] = sum_{i,p} inputs[b,i*4+p]*kernel[p,u,i,j]
//                + sum_{i,q} state[b,(i*32+u)*4+q]*rk[q,u,i,j]
// out_state[b,n,:] = { out[b,n], state[b,n,0..2] }
//
// R3 (recompile fix: __builtin_nontemporal_store needs ext_vector_type, not
// HIP float4): write-transaction fix. R2's GEMM showed WRITE_SIZE 200MB for
// 33.5MB of output (4B stores at 128B stride -> 16 blocks on different XCDs
// share each line -> amplification + false sharing), and prep_a's MA writes
// were 8B at 4MB stride. Now: GEMM writes contiguous Ct[u][b][j]; assemble3
// LDS-transposes Ct into out rows (j*32+u contiguous) and fuses out_state;
// prep_a_ma LDS-transposes state so reads AND writes are line-contiguous.
// Needs 136MB ws; falls back to R2 path (103MB) / R1 (33.5MB) / fp32.

typedef __attribute__((ext_vector_type(8))) short bf16x8;
typedef __attribute__((ext_vector_type(4))) float f32x4;

__device__ inline unsigned short f2bf(float x) {
    unsigned int u = __float_as_uint(x);
    return (unsigned short)((u + 0x7fffu + ((u >> 16) & 1u)) >> 16);
}

__device__ inline void cvt_store4(unsigned short* dst, float4 v) {
    float2 ab; ab.x = v.x; ab.y = v.y;
    float2 cd; cd.x = v.z; cd.y = v.w;
    __hip_bfloat162 lo = __float22bfloat162_rn(ab);   // v_cvt_pk_bf16_f32
    __hip_bfloat162 hi = __float22bfloat162_rn(cd);
    union { __hip_bfloat162 h2[2]; uint2 u2; } pk;
    pk.h2[0] = lo; pk.h2[1] = hi;
    *(uint2*)dst = pk.u2;
}

__device__ inline void cvt_store2(unsigned short* dst, float4 v) {
    // store v.x..v.w as 4 bf16 (8B)
    float2 ab; ab.x = v.x; ab.y = v.y;
    float2 cd; cd.x = v.z; cd.y = v.w;
    __hip_bfloat162 lo = __float22bfloat162_rn(ab);
    __hip_bfloat162 hi = __float22bfloat162_rn(cd);
    union { __hip_bfloat162 h2[2]; uint2 u2; } pk;
    pk.h2[0] = lo; pk.h2[1] = hi;
    *(uint2*)dst = pk.u2;
}

// ================= R3 PATH ====================================
// Workspace layout (bytes):
//   Wtt  : [32 u][2 jb][64 kt][128 j][32 k] bf16   = 33,554,432
//   At_ar: [16 mb][32 kt][64 b][32 k] bf16         =  2,097,152   (k 0..1023)
//   At_ma: [32 u][16 mb][32 ktp][64 b][32 k] bf16  = 67,108,864   (k 1024..2047)
//   Ct   : [32 u][1024 b][256 j] fp32              = 33,554,432
// total 136,314,880

// ---- prep_w2: Wtt[u][jb][kt][j][kk]
__global__ __launch_bounds__(256) void prep_w2(
    const float* __restrict__ kern,    // (4,32,256,256) [p][u][i][j]
    const float* __restrict__ rkern,   // (4,32,256,256) [q][u][i][j]
    unsigned short* __restrict__ Wtt)  // (32,2,64,128,32)
{
    const int u  = blockIdx.x;
    const int j0 = blockIdx.y * 64;
    const int zz = blockIdx.z;         // 0..31
    const int mm = zz >> 4;            // 0=kern, 1=rkern
    const int it = zz & 15;            // i-tile (16 i's -> 64 k's)
    const float* src = mm ? rkern : kern;
    const int kout = mm * 1024 + it * 64;

    __shared__ unsigned short T[64 * 72];   // [j][kk], pitch 72

    const int t  = threadIdx.x;
    const int jq = t & 3;
    const int ii = (t >> 2) & 15;
    const int pp = t >> 6;             // wave-uniform
    const int i  = it * 16 + ii;
    const int kk = ii * 4 + pp;        // 0..63
    const float* row = src + ((size_t)((pp * 32 + u) * 256 + i)) * 256 + j0 + jq * 16;
    #pragma unroll
    for (int s = 0; s < 4; ++s) {
        float4 v = *(const float4*)(row + s * 4);
        const int jb_ = jq * 16 + s * 4;
        T[(jb_ + 0) * 72 + kk] = f2bf(v.x);
        T[(jb_ + 1) * 72 + kk] = f2bf(v.y);
        T[(jb_ + 2) * 72 + kk] = f2bf(v.z);
        T[(jb_ + 3) * 72 + kk] = f2bf(v.w);
    }
    __syncthreads();
    const int j = t >> 2, q = t & 3;
    const int kglob = kout + q * 16;
    const int kt  = kglob >> 5;
    const int kk0 = kglob & 31;
    const int jb  = blockIdx.y >> 1;
    const int jloc = (blockIdx.y & 1) * 64 + j;
    unsigned short* dst = Wtt +
        ((((size_t)(u * 2 + jb) * 64 + kt) * 128 + jloc) * 32 + kk0);
    uint4 a = *(uint4*)&T[j * 72 + q * 16];
    uint4 b = *(uint4*)&T[j * 72 + q * 16 + 8];
    *(uint4*)dst = a;
    *(uint4*)(dst + 8) = b;
}

// ---- prep_a_ar: inputs -> At_ar (tiny, 4MB read)
__global__ __launch_bounds__(256) void prep_a_ar(
    const float* __restrict__ inputs,   // (1024,1024)
    unsigned short* __restrict__ At_ar) // (16,32,64,32)
{
    const size_t e = ((size_t)blockIdx.x * 256 + threadIdx.x) * 8;
    const int b = (int)(e >> 10), k = (int)(e & 1023);
    float4 v0 = *(const float4*)(inputs + e);
    float4 v1 = *(const float4*)(inputs + e + 4);
    const int mb = b >> 6, row = b & 63, kt = k >> 5, kk = k & 31;
    unsigned short* d = At_ar + (((size_t)(mb * 32 + kt) * 64 + row) * 32 + kk);
    cvt_store4(d, v0);
    cvt_store4(d + 4, v1);
}

// ---- prep_a_ma: state -> At_ma, both sides line-contiguous via LDS transpose
// grid (64 b-tiles of 16 rows, 32 i-tiles of 8 i), 256 thr
__global__ __launch_bounds__(256) void prep_a_ma(
    const float* __restrict__ state,    // (1024, 32768)
    unsigned short* __restrict__ At_ma) // (32,16,32,64,32)
{
    const int bt  = blockIdx.x;        // b0 = bt*16
    const int ktp = blockIdx.y;        // i0 = ktp*8
    const int t = threadIdx.x;
    __shared__ unsigned short L[32 * 16 * 40];  // [u][r] rows, pitch 40 shorts

    // read: 16 rows x 4KB fully contiguous; slot-XOR swizzle vs bank conflicts
    const int r = t >> 4;              // 0..15
    const int l = t & 15;
    const float* src = state + (size_t)(bt * 16 + r) * 32768 + ktp * 1024 + l * 4;
    #pragma unroll
    for (int s = 0; s < 16; ++s) {
        float4 v = *(const float4*)(src + s * 64);
        const int c4   = l + s * 16;     // (col_rel >> 2), 0..255
        const int u    = c4 & 31;
        const int iloc = c4 >> 5;        // 0..7
        const int slot = iloc ^ (u & 7); // 8B-slot swizzle
        cvt_store2(&L[(u * 16 + r) * 40 + slot * 4], v);
    }
    __syncthreads();
    // write: per (u, row) 64B contiguous; per wave 1KB contiguous
    const int mb   = bt >> 2;
    const int row0 = (bt & 3) * 16;
    const int part = t & 3;
    #pragma unroll
    for (int w = 0; w < 8; ++w) {
        const int pI = w * 64 + (t >> 2);  // 0..511 = (u,rr)
        const int u  = pI >> 4;
        const int rr = pI & 15;
        const int s0 = (2 * part) ^ (u & 7);
        const int s1 = (2 * part + 1) ^ (u & 7);
        uint2 d0 = *(const uint2*)&L[(u * 16 + rr) * 40 + s0 * 4];
        uint2 d1 = *(const uint2*)&L[(u * 16 + rr) * 40 + s1 * 4];
        uint4 o; o.x = d0.x; o.y = d0.y; o.z = d1.x; o.w = d1.y;
        unsigned short* dst = At_ma +
            ((((size_t)(u * 16 + mb) * 32 + ktp) * 64 + (row0 + rr)) * 32 + part * 8);
        *(uint4*)dst = o;
    }
}

// ---- GEMM v3: grid (16 mb, 2 jb, 32 u), 256 thr, 64x128 tile, BK=32
// identical to R2 GEMM but writes contiguous Ct[u][b][j]
#define PITCH 40   // bf16 pitch: 80B rows -> 2-way LDS aliasing only (free)

__global__ __launch_bounds__(256, 4) void arma_gemm_mfma2ct(
    const unsigned short* __restrict__ At_ar,   // (16,32,64,32) bf16
    const unsigned short* __restrict__ At_ma,   // (32,16,32,64,32) bf16
    const unsigned short* __restrict__ Wtt,     // (32,2,64,128,32) bf16
    float* __restrict__ Ct)                     // (32,1024,256)
{
    const int u  = blockIdx.z;
    const int mb = blockIdx.x;
    const int jb = blockIdx.y;
    const int b0 = mb * 64;
    const int j0 = jb * 128;
    const int t  = threadIdx.x;
    const int lane = t & 63;
    const int wn = (t >> 6) * 32;
    const int fm = lane & 15;
    const int kq = lane >> 4;

    __shared__ unsigned short Asr[2][64 * PITCH];
    __shared__ unsigned short Wsr[2][128 * PITCH];

    const int ar_row = t >> 2, ar_off = (t & 3) * 8;
    const int w_row  = t >> 1, w_off  = (t & 1) * 16;

    f32x4 acc[4][2];
    #pragma unroll
    for (int a = 0; a < 4; ++a)
        #pragma unroll
        for (int b = 0; b < 2; ++b)
            acc[a][b] = (f32x4)0.0f;

    const unsigned short* abase_ar = At_ar + (size_t)mb * 32 * 2048 + t * 8;
    const unsigned short* abase_ma = At_ma + (size_t)(u * 16 + mb) * 32 * 2048 + t * 8;
    const unsigned short* wbase    = Wtt + (size_t)(u * 2 + jb) * 64 * 4096 + t * 16;

    uint4 av, w0, w1;

    auto LOADW = [&](int kt) {
        const unsigned short* tw = wbase + (size_t)kt * 4096;
        w0 = *(const uint4*)tw;
        w1 = *(const uint4*)(tw + 8);
    };
    auto STORE = [&](int buf) {
        *(uint4*)&Asr[buf][ar_row * PITCH + ar_off] = av;
        unsigned short* wd = &Wsr[buf][w_row * PITCH + w_off];
        *(uint4*)wd = w0;
        *(uint4*)(wd + 8) = w1;
    };
    auto COMPUTE = [&](int buf) {
        bf16x8 af[4], bfr[2];
        #pragma unroll
        for (int mt = 0; mt < 4; ++mt)
            af[mt] = *(const bf16x8*)&Asr[buf][(mt * 16 + fm) * PITCH + kq * 8];
        #pragma unroll
        for (int nt = 0; nt < 2; ++nt)
            bfr[nt] = *(const bf16x8*)&Wsr[buf][(wn + nt * 16 + fm) * PITCH + kq * 8];
        #pragma unroll
        for (int mt = 0; mt < 4; ++mt)
            #pragma unroll
            for (int nt = 0; nt < 2; ++nt)
                acc[mt][nt] = __builtin_amdgcn_mfma_f32_16x16x32_bf16(
                    af[mt], bfr[nt], acc[mt][nt], 0, 0, 0);
    };

    av = *(const uint4*)abase_ar;
    LOADW(0);
    STORE(0);
    __syncthreads();

    int cur = 0;
    for (int kt = 0; kt < 63; ++kt) {
        const int kn = kt + 1;
        const unsigned short* ta = (kn < 32) ? (abase_ar + (size_t)kn * 2048)
                                             : (abase_ma + (size_t)(kn - 32) * 2048);
        av = *(const uint4*)ta;
        LOADW(kn);
        COMPUTE(cur);
        STORE(cur ^ 1);
        __syncthreads();
        cur ^= 1;
    }
    COMPUTE(cur);

    // Epilogue: contiguous Ct[u][b][j]; 16 fm-lanes -> 64B runs, no line sharing
    #pragma unroll
    for (int mt = 0; mt < 4; ++mt) {
        const int rbase = b0 + mt * 16 + kq * 4;
        #pragma unroll
        for (int nt = 0; nt < 2; ++nt) {
            const int col = j0 + wn + nt * 16 + fm;
            float* op = Ct + (size_t)u * 262144 + (size_t)rbase * 256 + col;
            op[0]       = acc[mt][nt][0];
            op[256]     = acc[mt][nt][1];
            op[2 * 256] = acc[mt][nt][2];
            op[3 * 256] = acc[mt][nt][3];
        }
    }
}

// ---- assemble3: Ct -> out (contiguous rows via LDS transpose) + out_state
__global__ __launch_bounds__(256) void arma_assemble3(
    const float* __restrict__ state,    // (1024, 32768)
    const float* __restrict__ Ct,       // (32, 1024, 256)
    float* __restrict__ out,            // (1024, 8192)
    float* __restrict__ out_state)      // (1024, 8192, 4)
{
    const int b = blockIdx.x;
    const int t = threadIdx.x;
    __shared__ float L[256 * 33];       // [j][u], pitch 33: conflict-free both ways
    for (int u = 0; u < 32; ++u)
        L[t * 33 + u] = Ct[((size_t)u * 1024 + b) * 256 + t];
    __syncthreads();
    const float* srow = state + (size_t)b * 32768;
    float* orow  = out + (size_t)b * 8192;
    float* osrow = out_state + (size_t)b * 32768;
    for (int w = 0; w < 32; ++w) {
        const int n = w * 256 + t;
        const float o = L[(n >> 5) * 33 + (n & 31)];
        const f32x4 s = *(const f32x4*)(srow + (size_t)n * 4);
        __builtin_nontemporal_store(o, orow + n);
        f32x4 rv = { o, s[0], s[1], s[2] };
        __builtin_nontemporal_store(rv, (f32x4*)(osrow + (size_t)n * 4));
    }
}

// ================= R2 PATH (fallback, 103MB ws) =====================
__global__ __launch_bounds__(256) void prep_a(
    const float* __restrict__ inputs,
    const float* __restrict__ state,
    unsigned short* __restrict__ At_ar,
    unsigned short* __restrict__ At_ma)
{
    const int bid = blockIdx.x;
    if (bid < 512) {
        const size_t e = ((size_t)bid * 256 + threadIdx.x) * 8;
        const int b = (int)(e >> 10), k = (int)(e & 1023);
        float4 v0 = *(const float4*)(inputs + e);
        float4 v1 = *(const float4*)(inputs + e + 4);
        const int mb = b >> 6, row = b & 63, kt = k >> 5, kk = k & 31;
        unsigned short* d = At_ar + (((size_t)(mb * 32 + kt) * 64 + row) * 32 + kk);
        cvt_store4(d, v0);
        cvt_store4(d + 4, v1);
    } else {
        const size_t e4 = (size_t)(bid - 512) * 256 + threadIdx.x;
        const int b = (int)(e4 >> 13), col4 = (int)(e4 & 8191);
        const int i = col4 >> 5, u = col4 & 31;
        float4 v = *(const float4*)(state + e4 * 4);
        const int mb = b >> 6, row = b & 63;
        const int ktp = i >> 3;
        const int kk = (i * 4) & 31;
        unsigned short* d = At_ma +
            ((((size_t)(u * 16 + mb) * 32 + ktp) * 64 + row) * 32 + kk);
        cvt_store2(d, v);
    }
}

__global__ __launch_bounds__(256, 4) void arma_gemm_mfma2(
    const unsigned short* __restrict__ At_ar,
    const unsigned short* __restrict__ At_ma,
    const unsigned short* __restrict__ Wtt,
    float* __restrict__ out)
{
    const int u  = blockIdx.z;
    const int mb = blockIdx.x;
    const int jb = blockIdx.y;
    const int b0 = mb * 64;
    const int j0 = jb * 128;
    const int t  = threadIdx.x;
    const int lane = t & 63;
    const int wn = (t >> 6) * 32;
    const int fm = lane & 15;
    const int kq = lane >> 4;

    __shared__ unsigned short Asr[2][64 * PITCH];
    __shared__ unsigned short Wsr[2][128 * PITCH];

    const int ar_row = t >> 2, ar_off = (t & 3) * 8;
    const int w_row  = t >> 1, w_off  = (t & 1) * 16;

    f32x4 acc[4][2];
    #pragma unroll
    for (int a = 0; a < 4; ++a)
        #pragma unroll
        for (int b = 0; b < 2; ++b)
            acc[a][b] = (f32x4)0.0f;

    const unsigned short* abase_ar = At_ar + (size_t)mb * 32 * 2048 + t * 8;
    const unsigned short* abase_ma = At_ma + (size_t)(u * 16 + mb) * 32 * 2048 + t * 8;
    const unsigned short* wbase    = Wtt + (size_t)(u * 2 + jb) * 64 * 4096 + t * 16;

    uint4 av, w0, w1;

    auto LOADW = [&](int kt) {
        const unsigned short* tw = wbase + (size_t)kt * 4096;
        w0 = *(const uint4*)tw;
        w1 = *(const uint4*)(tw + 8);
    };
    auto STORE = [&](int buf) {
        *(uint4*)&Asr[buf][ar_row * PITCH + ar_off] = av;
        unsigned short* wd = &Wsr[buf][w_row * PITCH + w_off];
        *(uint4*)wd = w0;
        *(uint4*)(wd + 8) = w1;
    };
    auto COMPUTE = [&](int buf) {
        bf16x8 af[4], bfr[2];
        #pragma unroll
        for (int mt = 0; mt < 4; ++mt)
            af[mt] = *(const bf16x8*)&Asr[buf][(mt * 16 + fm) * PITCH + kq * 8];
        #pragma unroll
        for (int nt = 0; nt < 2; ++nt)
            bfr[nt] = *(const bf16x8*)&Wsr[buf][(wn + nt * 16 + fm) * PITCH + kq * 8];
        #pragma unroll
        for (int mt = 0; mt < 4; ++mt)
            #pragma unroll
            for (int nt = 0; nt < 2; ++nt)
                acc[mt][nt] = __builtin_amdgcn_mfma_f32_16x16x32_bf16(
                    af[mt], bfr[nt], acc[mt][nt], 0, 0, 0);
    };

    av = *(const uint4*)abase_ar;
    LOADW(0);
    STORE(0);
    __syncthreads();

    int cur = 0;
    for (int kt = 0; kt < 63; ++kt) {
        const int kn = kt + 1;
        const unsigned short* ta = (kn < 32) ? (abase_ar + (size_t)kn * 2048)
                                             : (abase_ma + (size_t)(kn - 32) * 2048);
        av = *(const uint4*)ta;
        LOADW(kn);
        COMPUTE(cur);
        STORE(cur ^ 1);
        __syncthreads();
        cur ^= 1;
    }
    COMPUTE(cur);

    #pragma unroll
    for (int mt = 0; mt < 4; ++mt) {
        const int rbase = b0 + mt * 16 + kq * 4;
        #pragma unroll
        for (int nt = 0; nt < 2; ++nt) {
            const int col = j0 + wn + nt * 16 + fm;
            float* op = out + (size_t)rbase * 8192 + (size_t)col * 32 + u;
            op[0]        = acc[mt][nt][0];
            op[8192]     = acc[mt][nt][1];
            op[2 * 8192] = acc[mt][nt][2];
            op[3 * 8192] = acc[mt][nt][3];
        }
    }
}

// ================= R1 PATH (fallback, 33.5MB ws) =====================
__global__ __launch_bounds__(256) void prep_w(
    const float* __restrict__ kern,
    const float* __restrict__ rkern,
    unsigned short* __restrict__ Wt)   // (32,256,2048)
{
    const int u  = blockIdx.x;
    const int j0 = blockIdx.y * 64;
    const int zz = blockIdx.z;
    const int mm = zz >> 4;
    const int it = zz & 15;
    const float* src = mm ? rkern : kern;
    const int kout = mm * 1024 + it * 64;

    __shared__ unsigned short T[64 * 72];

    const int t  = threadIdx.x;
    const int jq = t & 3;
    const int ii = (t >> 2) & 15;
    const int pp = t >> 6;
    const int i  = it * 16 + ii;
    const int kk = ii * 4 + pp;
    const float* row = src + ((size_t)((pp * 32 + u) * 256 + i)) * 256 + j0 + jq * 16;
    #pragma unroll
    for (int s = 0; s < 4; ++s) {
        float4 v = *(const float4*)(row + s * 4);
        const int jb = jq * 16 + s * 4;
        T[(jb + 0) * 72 + kk] = f2bf(v.x);
        T[(jb + 1) * 72 + kk] = f2bf(v.y);
        T[(jb + 2) * 72 + kk] = f2bf(v.z);
        T[(jb + 3) * 72 + kk] = f2bf(v.w);
    }
    __syncthreads();
    const int j = t >> 2, q = t & 3;
    unsigned short* dst = Wt + ((size_t)(u * 256 + j0 + j)) * 2048 + kout + q * 16;
    uint4 a = *(uint4*)&T[j * 72 + q * 16];
    uint4 b = *(uint4*)&T[j * 72 + q * 16 + 8];
    *(uint4*)dst = a;
    *(uint4*)(dst + 8) = b;
}

__global__ __launch_bounds__(256, 4) void arma_gemm_mfma(
    const float* __restrict__ inputs,
    const float* __restrict__ state,
    const unsigned short* __restrict__ Wt,
    float* __restrict__ out)
{
    const int u  = blockIdx.z;
    const int b0 = blockIdx.x * 64;
    const int j0 = blockIdx.y * 128;
    const int t  = threadIdx.x;
    const int lane = t & 63;
    const int wn = (t >> 6) * 32;
    const int fm = lane & 15;
    const int kq = lane >> 4;

    __shared__ unsigned short Asr[2][64 * PITCH];
    __shared__ unsigned short Wsr[2][128 * PITCH];

    const int arow = t & 63;
    const int aseg = t >> 6;
    const int wrow = t >> 1;
    const int wseg = t & 1;

    f32x4 acc[4][2];
    #pragma unroll
    for (int a = 0; a < 4; ++a)
        #pragma unroll
        for (int b = 0; b < 2; ++b)
            acc[a][b] = (f32x4)0.0f;

    const unsigned short* wsrc = Wt + ((size_t)(u * 256 + j0 + wrow)) * 2048 + wseg * 16;
    const float* in_row = inputs + (size_t)(b0 + arow) * 1024 + aseg * 8;
    const float* st_row = state + (size_t)(b0 + arow) * 32768 + (size_t)u * 4;

    float4 a0, a1;
    uint4 w0, w1;

    auto LOAD = [&](int kt) {
        if (kt < 1024) {
            const float* s = in_row + kt;
            a0 = *(const float4*)(s);
            a1 = *(const float4*)(s + 4);
        } else {
            const int kk = kt - 1024 + aseg * 8;
            const float* s = st_row + (size_t)(kk >> 2) * 128;
            a0 = *(const float4*)(s);
            a1 = *(const float4*)(s + 128);
        }
        w0 = *(const uint4*)(wsrc + kt);
        w1 = *(const uint4*)(wsrc + kt + 8);
    };
    auto STORE = [&](int buf) {
        unsigned short* ad = &Asr[buf][arow * PITCH + aseg * 8];
        cvt_store4(ad + 0, a0);
        cvt_store4(ad + 4, a1);
        unsigned short* wd = &Wsr[buf][wrow * PITCH + wseg * 16];
        *(uint4*)wd = w0;
        *(uint4*)(wd + 8) = w1;
    };
    auto COMPUTE = [&](int buf) {
        bf16x8 af[4], bfr[2];
        #pragma unroll
        for (int mt = 0; mt < 4; ++mt)
            af[mt] = *(const bf16x8*)&Asr[buf][(mt * 16 + fm) * PITCH + kq * 8];
        #pragma unroll
        for (int nt = 0; nt < 2; ++nt)
            bfr[nt] = *(const bf16x8*)&Wsr[buf][(wn + nt * 16 + fm) * PITCH + kq * 8];
        #pragma unroll
        for (int mt = 0; mt < 4; ++mt)
            #pragma unroll
            for (int nt = 0; nt < 2; ++nt)
                acc[mt][nt] = __builtin_amdgcn_mfma_f32_16x16x32_bf16(
                    af[mt], bfr[nt], acc[mt][nt], 0, 0, 0);
    };

    LOAD(0);
    STORE(0);
    __syncthreads();

    int cur = 0;
    for (int kt = 0; kt < 2048 - 32; kt += 32) {
        LOAD(kt + 32);
        COMPUTE(cur);
        STORE(cur ^ 1);
        __syncthreads();
        cur ^= 1;
    }
    COMPUTE(cur);

    #pragma unroll
    for (int mt = 0; mt < 4; ++mt) {
        const int rbase = b0 + mt * 16 + kq * 4;
        #pragma unroll
        for (int nt = 0; nt < 2; ++nt) {
            const int col = j0 + wn + nt * 16 + fm;
            float* op = out + (size_t)rbase * 8192 + (size_t)col * 32 + u;
            op[0]        = acc[mt][nt][0];
            op[8192]     = acc[mt][nt][1];
            op[2 * 8192] = acc[mt][nt][2];
            op[3 * 8192] = acc[mt][nt][3];
        }
    }
}

// ---------------- fp32 fallback GEMM
#define BM 64
#define BN 64
#define BKF 16
#define LDP 68

__global__ __launch_bounds__(256) void arma_gemm_f32(
    const float* __restrict__ inputs, const float* __restrict__ state,
    const float* __restrict__ kern, const float* __restrict__ rkern,
    float* __restrict__ out)
{
    const int u = blockIdx.z, b0 = blockIdx.x * BM, j0 = blockIdx.y * BN;
    const int tid = threadIdx.x;
    __shared__ float As[BKF][LDP];
    __shared__ float Ws[BKF][LDP];
    const int tx = tid & 15, ty = tid >> 4;
    const int arow = tid >> 2, ak4 = (tid & 3) * 4;
    const int wrow = tid >> 4, wj = (tid & 15) * 4;
    float acc[4][4] = {{0.f}};
    for (int kt = 0; kt < 1024; kt += BKF) {
        const float4 av = *(const float4*)(inputs + (size_t)(b0 + arow) * 1024 + kt + ak4);
        As[ak4 + 0][arow] = av.x; As[ak4 + 1][arow] = av.y;
        As[ak4 + 2][arow] = av.z; As[ak4 + 3][arow] = av.w;
        const int ip = kt + wrow;
        const float4 wv = *(const float4*)(kern + ((size_t)(((ip & 3) * 32 + u) * 256 + (ip >> 2))) * 256 + j0 + wj);
        *(float4*)&Ws[wrow][wj] = wv;
        __syncthreads();
        #pragma unroll
        for (int kk = 0; kk < BKF; ++kk) {
            const float4 a4 = *(const float4*)&As[kk][ty * 4];
            const float4 w4 = *(const float4*)&Ws[kk][tx * 4];
            acc[0][0] += a4.x * w4.x; acc[0][1] += a4.x * w4.y; acc[0][2] += a4.x * w4.z; acc[0][3] += a4.x * w4.w;
            acc[1][0] += a4.y * w4.x; acc[1][1] += a4.y * w4.y; acc[1][2] += a4.y * w4.z; acc[1][3] += a4.y * w4.w;
            acc[2][0] += a4.z * w4.x; acc[2][1] += a4.z * w4.y; acc[2][2] += a4.z * w4.z; acc[2][3] += a4.z * w4.w;
            acc[3][0] += a4.w * w4.x; acc[3][1] += a4.w * w4.y; acc[3][2] += a4.w * w4.z; acc[3][3] += a4.w * w4.w;
        }
        __syncthreads();
    }
    for (int kt = 0; kt < 1024; kt += BKF) {
        const int i = (kt >> 2) + (tid & 3);
        const float4 av = *(const float4*)(state + (size_t)(b0 + arow) * 32768 + (size_t)(i * 32 + u) * 4);
        As[ak4 + 0][arow] = av.x; As[ak4 + 1][arow] = av.y;
        As[ak4 + 2][arow] = av.z; As[ak4 + 3][arow] = av.w;
        const int iq = kt + wrow;
        const float4 wv = *(const float4*)(rkern + ((size_t)(((iq & 3) * 32 + u) * 256 + (iq >> 2))) * 256 + j0 + wj);
        *(float4*)&Ws[wrow][wj] = wv;
        __syncthreads();
        #pragma unroll
        for (int kk = 0; kk < BKF; ++kk) {
            const float4 a4 = *(const float4*)&As[kk][ty * 4];
            const float4 w4 = *(const float4*)&Ws[kk][tx * 4];
            acc[0][0] += a4.x * w4.x; acc[0][1] += a4.x * w4.y; acc[0][2] += a4.x * w4.z; acc[0][3] += a4.x * w4.w;
            acc[1][0] += a4.y * w4.x; acc[1][1] += a4.y * w4.y; acc[1][2] += a4.y * w4.z; acc[1][3] += a4.y * w4.w;
            acc[2][0] += a4.z * w4.x; acc[2][1] += a4.z * w4.y; acc[2][2] += a4.z * w4.z; acc[2][3] += a4.z * w4.w;
            acc[3][0] += a4.w * w4.x; acc[3][1] += a4.w * w4.y; acc[3][2] += a4.w * w4.z; acc[3][3] += a4.w * w4.w;
        }
        __syncthreads();
    }
    const int bb = b0 + ty * 4, jj = j0 + tx * 4;
    #pragma unroll
    for (int r = 0; r < 4; ++r)
        #pragma unroll
        for (int c = 0; c < 4; ++c)
            out[(size_t)(bb + r) * 8192 + (size_t)(jj + c) * 32 + u] = acc[r][c];
}

// ---------------- Assemble (fallback paths)
__global__ __launch_bounds__(256) void arma_assemble2(
    const float* __restrict__ state,
    const float* __restrict__ out,
    float* __restrict__ out_state)
{
    const size_t i = (size_t)blockIdx.x * 256 + threadIdx.x;
    const f32x4 o = *(const f32x4*)(out + i * 4);
    const float* sp = state + i * 16;
    const f32x4 s0 = *(const f32x4*)(sp + 0);
    const f32x4 s1 = *(const f32x4*)(sp + 4);
    const f32x4 s2 = *(const f32x4*)(sp + 8);
    const f32x4 s3 = *(const f32x4*)(sp + 12);
    f32x4 r0 = { o[0], s0[0], s0[1], s0[2] };
    f32x4 r1 = { o[1], s1[0], s1[1], s1[2] };
    f32x4 r2 = { o[2], s2[0], s2[1], s2[2] };
    f32x4 r3 = { o[3], s3[0], s3[1], s3[2] };
    f32x4* dp = (f32x4*)(out_state + i * 16);
    __builtin_nontemporal_store(r0, dp + 0);
    __builtin_nontemporal_store(r1, dp + 1);
    __builtin_nontemporal_store(r2, dp + 2);
    __builtin_nontemporal_store(r3, dp + 3);
}

extern "C" void kernel_launch(void* const* d_in, const int* in_sizes, int n_in,
                              void* d_out, int out_size, void* d_ws, size_t ws_size,
                              hipStream_t stream) {
    const float* inputs = (const float*)d_in[0];
    const float* state  = (const float*)d_in[1];
    const float* kern   = (const float*)d_in[2];
    const float* rkern  = (const float*)d_in[3];

    float* out       = (float*)d_out;
    float* out_state = (float*)d_out + 8388608;

    const size_t WTT_BYTES  = (size_t)32 * 2 * 64 * 128 * 32 * 2;      //  33,554,432
    const size_t ATAR_BYTES = (size_t)16 * 32 * 64 * 32 * 2;           //   2,097,152
    const size_t ATMA_BYTES = (size_t)32 * 16 * 32 * 64 * 32 * 2;      //  67,108,864
    const size_t CT_BYTES   = (size_t)32 * 1024 * 256 * 4;             //  33,554,432
    const size_t R2_BYTES   = WTT_BYTES + ATAR_BYTES + ATMA_BYTES;     // 102,760,448
    const size_t R3_BYTES   = R2_BYTES + CT_BYTES;                     // 136,314,880
    const size_t WT_BYTES   = (size_t)32 * 256 * 2048 * 2;             //  33,554,432

    if (ws_size >= R3_BYTES) {
        unsigned short* Wtt   = (unsigned short*)d_ws;
        unsigned short* At_ar = (unsigned short*)((char*)d_ws + WTT_BYTES);
        unsigned short* At_ma = (unsigned short*)((char*)d_ws + WTT_BYTES + ATAR_BYTES);
        float* Ct             = (float*)((char*)d_ws + R2_BYTES);
        prep_w2<<<dim3(32, 4, 32), 256, 0, stream>>>(kern, rkern, Wtt);
        prep_a_ar<<<dim3(512), 256, 0, stream>>>(inputs, At_ar);
        prep_a_ma<<<dim3(64, 32), 256, 0, stream>>>(state, At_ma);
        arma_gemm_mfma2ct<<<dim3(16, 2, 32), 256, 0, stream>>>(At_ar, At_ma, Wtt, Ct);
        arma_assemble3<<<dim3(1024), 256, 0, stream>>>(state, Ct, out, out_state);
    } else if (ws_size >= R2_BYTES) {
        unsigned short* Wtt   = (unsigned short*)d_ws;
        unsigned short* At_ar = (unsigned short*)((char*)d_ws + WTT_BYTES);
        unsigned short* At_ma = (unsigned short*)((char*)d_ws + WTT_BYTES + ATAR_BYTES);
        prep_w2<<<dim3(32, 4, 32), 256, 0, stream>>>(kern, rkern, Wtt);
        prep_a<<<dim3(512 + 32768, 1, 1), 256, 0, stream>>>(inputs, state, At_ar, At_ma);
        arma_gemm_mfma2<<<dim3(16, 2, 32), 256, 0, stream>>>(At_ar, At_ma, Wtt, out);
        arma_assemble2<<<8388608 / 4 / 256, 256, 0, stream>>>(state, out, out_state);
    } else if (ws_size >= WT_BYTES) {
        unsigned short* Wt = (unsigned short*)d_ws;
        prep_w<<<dim3(32, 4, 32), 256, 0, stream>>>(kern, rkern, Wt);
        arma_gemm_mfma<<<dim3(16, 2, 32), 256, 0, stream>>>(inputs, state, Wt, out);
        arma_assemble2<<<8388608 / 4 / 256, 256, 0, stream>>>(state, out, out_state);
    } else {
        arma_gemm_f32<<<dim3(16, 4, 32), 256, 0, stream>>>(inputs, state, kern, rkern, out);
        arma_assemble2<<<8388608 / 4 / 256, 256, 0, stream>>>(state, out, out_state);
    }
}

// Round 6
// 425.888 us; speedup vs baseline: 1.4898x; 1.0341x over previous
//
#include <hip/hip_runtime.h>
#include <hip/hip_bf16.h>

// ArmaCell: B=1024, K=256, UNITS=32, P=4, Q=4
// out[b, j*32+u] = sum_{i,p} inputs[b,i*4+p]*kernel[p,u,i,j]
//                + sum_{i,q} state[b,(i*32+u)*4+q]*rk[q,u,i,j]
// out_state[b,n,:] = { out[b,n], state[b,n,0..2] }
//
// R5: GEMM is staging-BW bound: 537MB of Wtt re-reads cross XCDs (each
// (u,jb) W-slice read by 16 mb-blocks round-robined over 8 XCDs -> L3/HBM).
// Fix: XCD-aware swizzle so all mb-blocks of a (u,jb) pair land on ONE XCD
// (per-XCD W footprint 4.2MB ~ L2) => W re-reads served from L2 @34.5TB/s.
// Also merged the 3 prep kernels into one launch (overlap + fewer gaps).

typedef __attribute__((ext_vector_type(8))) short bf16x8;
typedef __attribute__((ext_vector_type(4))) float f32x4;

__device__ inline unsigned short f2bf(float x) {
    unsigned int u = __float_as_uint(x);
    return (unsigned short)((u + 0x7fffu + ((u >> 16) & 1u)) >> 16);
}

__device__ inline void cvt_store4(unsigned short* dst, float4 v) {
    float2 ab; ab.x = v.x; ab.y = v.y;
    float2 cd; cd.x = v.z; cd.y = v.w;
    __hip_bfloat162 lo = __float22bfloat162_rn(ab);   // v_cvt_pk_bf16_f32
    __hip_bfloat162 hi = __float22bfloat162_rn(cd);
    union { __hip_bfloat162 h2[2]; uint2 u2; } pk;
    pk.h2[0] = lo; pk.h2[1] = hi;
    *(uint2*)dst = pk.u2;
}

__device__ inline void cvt_store2(unsigned short* dst, float4 v) {
    // store v.x..v.w as 4 bf16 (8B)
    float2 ab; ab.x = v.x; ab.y = v.y;
    float2 cd; cd.x = v.z; cd.y = v.w;
    __hip_bfloat162 lo = __float22bfloat162_rn(ab);
    __hip_bfloat162 hi = __float22bfloat162_rn(cd);
    union { __hip_bfloat162 h2[2]; uint2 u2; } pk;
    pk.h2[0] = lo; pk.h2[1] = hi;
    *(uint2*)dst = pk.u2;
}

// ================= R5 PATH ====================================
// Workspace layout (bytes):
//   Wtt  : [32 u][2 jb][64 kt][128 j][32 k] bf16   = 33,554,432
//   At_ar: [16 mb][32 kt][64 b][32 k] bf16         =  2,097,152   (k 0..1023)
//   At_ma: [32 u][16 mb][32 ktp][64 b][32 k] bf16  = 67,108,864   (k 1024..2047)
//   Ct   : [32 u][1024 b][256 j] fp32              = 33,554,432
// total 136,314,880

// ---- prep_all: merged W-prep / AR-prep / MA-prep (block-range dispatch)
// blocks [0,4096): Wtt;  [4096,4608): At_ar;  [4608,6656): At_ma
__global__ __launch_bounds__(256) void prep_all(
    const float* __restrict__ kern,     // (4,32,256,256) [p][u][i][j]
    const float* __restrict__ rkern,    // (4,32,256,256) [q][u][i][j]
    const float* __restrict__ inputs,   // (1024,1024)
    const float* __restrict__ state,    // (1024,32768)
    unsigned short* __restrict__ Wtt,   // (32,2,64,128,32)
    unsigned short* __restrict__ At_ar, // (16,32,64,32)
    unsigned short* __restrict__ At_ma) // (32,16,32,64,32)
{
    __shared__ char smem_raw[40960];
    const int bid = blockIdx.x;
    const int t = threadIdx.x;

    if (bid < 4096) {
        // ---------------- W prep (was prep_w2), grid (32u, 4jy, 32zz)
        unsigned short* T = (unsigned short*)smem_raw;   // [64 j][72 pitch]
        const int u  = bid & 31;
        const int jy = (bid >> 5) & 3;
        const int zz = bid >> 7;           // 0..31
        const int j0 = jy * 64;
        const int mm = zz >> 4;            // 0=kern, 1=rkern
        const int it = zz & 15;            // i-tile (16 i's -> 64 k's)
        const float* src = mm ? rkern : kern;
        const int kout = mm * 1024 + it * 64;

        const int jq = t & 3;
        const int ii = (t >> 2) & 15;
        const int pp = t >> 6;             // wave-uniform
        const int i  = it * 16 + ii;
        const int kk = ii * 4 + pp;        // 0..63
        const float* row = src + ((size_t)((pp * 32 + u) * 256 + i)) * 256 + j0 + jq * 16;
        #pragma unroll
        for (int s = 0; s < 4; ++s) {
            float4 v = *(const float4*)(row + s * 4);
            const int jb_ = jq * 16 + s * 4;
            T[(jb_ + 0) * 72 + kk] = f2bf(v.x);
            T[(jb_ + 1) * 72 + kk] = f2bf(v.y);
            T[(jb_ + 2) * 72 + kk] = f2bf(v.z);
            T[(jb_ + 3) * 72 + kk] = f2bf(v.w);
        }
        __syncthreads();
        const int j = t >> 2, q = t & 3;
        const int kglob = kout + q * 16;
        const int kt  = kglob >> 5;
        const int kk0 = kglob & 31;
        const int jbo = jy >> 1;
        const int jloc = (jy & 1) * 64 + j;
        unsigned short* dst = Wtt +
            ((((size_t)(u * 2 + jbo) * 64 + kt) * 128 + jloc) * 32 + kk0);
        uint4 a = *(uint4*)&T[j * 72 + q * 16];
        uint4 b = *(uint4*)&T[j * 72 + q * 16 + 8];
        *(uint4*)dst = a;
        *(uint4*)(dst + 8) = b;
    } else if (bid < 4608) {
        // ---------------- AR prep (was prep_a_ar)
        const int b2 = bid - 4096;
        const size_t e = ((size_t)b2 * 256 + t) * 8;
        const int b = (int)(e >> 10), k = (int)(e & 1023);
        float4 v0 = *(const float4*)(inputs + e);
        float4 v1 = *(const float4*)(inputs + e + 4);
        const int mb = b >> 6, row = b & 63, kt = k >> 5, kk = k & 31;
        unsigned short* d = At_ar + (((size_t)(mb * 32 + kt) * 64 + row) * 32 + kk);
        cvt_store4(d, v0);
        cvt_store4(d + 4, v1);
    } else {
        // ---------------- MA prep (was prep_a_ma), grid (64 bt, 32 ktp)
        unsigned short* L = (unsigned short*)smem_raw;   // [32u*16r][40 pitch]
        const int b2  = bid - 4608;        // 0..2047
        const int bt  = b2 & 63;           // b0 = bt*16
        const int ktp = b2 >> 6;           // i0 = ktp*8

        // read: 16 rows x 4KB fully contiguous; slot-XOR swizzle vs bank conflicts
        const int r = t >> 4;              // 0..15
        const int l = t & 15;
        const float* src = state + (size_t)(bt * 16 + r) * 32768 + ktp * 1024 + l * 4;
        #pragma unroll
        for (int s = 0; s < 16; ++s) {
            float4 v = *(const float4*)(src + s * 64);
            const int c4   = l + s * 16;     // (col_rel >> 2), 0..255
            const int u    = c4 & 31;
            const int iloc = c4 >> 5;        // 0..7
            const int slot = iloc ^ (u & 7); // 8B-slot swizzle
            cvt_store2(&L[(u * 16 + r) * 40 + slot * 4], v);
        }
        __syncthreads();
        // write: per (u, row) 64B contiguous; per wave 1KB contiguous
        const int mb   = bt >> 2;
        const int row0 = (bt & 3) * 16;
        const int part = t & 3;
        #pragma unroll
        for (int w = 0; w < 8; ++w) {
            const int pI = w * 64 + (t >> 2);  // 0..511 = (u,rr)
            const int u  = pI >> 4;
            const int rr = pI & 15;
            const int s0 = (2 * part) ^ (u & 7);
            const int s1 = (2 * part + 1) ^ (u & 7);
            uint2 d0 = *(const uint2*)&L[(u * 16 + rr) * 40 + s0 * 4];
            uint2 d1 = *(const uint2*)&L[(u * 16 + rr) * 40 + s1 * 4];
            uint4 o; o.x = d0.x; o.y = d0.y; o.z = d1.x; o.w = d1.y;
            unsigned short* dst = At_ma +
                ((((size_t)(u * 16 + mb) * 32 + ktp) * 64 + (row0 + rr)) * 32 + part * 8);
            *(uint4*)dst = o;
        }
    }
}

// ---- GEMM: 1D grid 1024, XCD-swizzled decode; 64x128 tile, BK=32, dbuf
#define PITCH 40   // bf16 pitch: 80B rows -> 2-way LDS aliasing only (free)

__global__ __launch_bounds__(256, 4) void arma_gemm_mfma2ct(
    const unsigned short* __restrict__ At_ar,   // (16,32,64,32) bf16
    const unsigned short* __restrict__ At_ma,   // (32,16,32,64,32) bf16
    const unsigned short* __restrict__ Wtt,     // (32,2,64,128,32) bf16
    float* __restrict__ Ct)                     // (32,1024,256)
{
    // XCD swizzle: dispatch round-robins linear id over 8 XCDs; give each XCD
    // 8 complete (u,jb) pairs so all 16 mb-blocks of a pair share one L2.
    const int bid  = blockIdx.x;
    const int xcd  = bid & 7;
    const int slot = bid >> 3;           // 0..127
    const int pair = xcd * 8 + (slot & 7);   // 0..63
    const int mb   = slot >> 3;          // 0..15
    const int u    = pair >> 1;
    const int jb   = pair & 1;
    const int b0 = mb * 64;
    const int j0 = jb * 128;
    const int t  = threadIdx.x;
    const int lane = t & 63;
    const int wn = (t >> 6) * 32;
    const int fm = lane & 15;
    const int kq = lane >> 4;

    __shared__ unsigned short Asr[2][64 * PITCH];
    __shared__ unsigned short Wsr[2][128 * PITCH];

    const int ar_row = t >> 2, ar_off = (t & 3) * 8;
    const int w_row  = t >> 1, w_off  = (t & 1) * 16;

    f32x4 acc[4][2];
    #pragma unroll
    for (int a = 0; a < 4; ++a)
        #pragma unroll
        for (int b = 0; b < 2; ++b)
            acc[a][b] = (f32x4)0.0f;

    const unsigned short* abase_ar = At_ar + (size_t)mb * 32 * 2048 + t * 8;
    const unsigned short* abase_ma = At_ma + (size_t)(u * 16 + mb) * 32 * 2048 + t * 8;
    const unsigned short* wbase    = Wtt + (size_t)(u * 2 + jb) * 64 * 4096 + t * 16;

    uint4 av, w0, w1;

    auto LOADW = [&](int kt) {
        const unsigned short* tw = wbase + (size_t)kt * 4096;
        w0 = *(const uint4*)tw;
        w1 = *(const uint4*)(tw + 8);
    };
    auto STORE = [&](int buf) {
        *(uint4*)&Asr[buf][ar_row * PITCH + ar_off] = av;
        unsigned short* wd = &Wsr[buf][w_row * PITCH + w_off];
        *(uint4*)wd = w0;
        *(uint4*)(wd + 8) = w1;
    };
    auto COMPUTE = [&](int buf) {
        bf16x8 af[4], bfr[2];
        #pragma unroll
        for (int mt = 0; mt < 4; ++mt)
            af[mt] = *(const bf16x8*)&Asr[buf][(mt * 16 + fm) * PITCH + kq * 8];
        #pragma unroll
        for (int nt = 0; nt < 2; ++nt)
            bfr[nt] = *(const bf16x8*)&Wsr[buf][(wn + nt * 16 + fm) * PITCH + kq * 8];
        #pragma unroll
        for (int mt = 0; mt < 4; ++mt)
            #pragma unroll
            for (int nt = 0; nt < 2; ++nt)
                acc[mt][nt] = __builtin_amdgcn_mfma_f32_16x16x32_bf16(
                    af[mt], bfr[nt], acc[mt][nt], 0, 0, 0);
    };

    av = *(const uint4*)abase_ar;
    LOADW(0);
    STORE(0);
    __syncthreads();

    int cur = 0;
    for (int kt = 0; kt < 63; ++kt) {
        const int kn = kt + 1;
        const unsigned short* ta = (kn < 32) ? (abase_ar + (size_t)kn * 2048)
                                             : (abase_ma + (size_t)(kn - 32) * 2048);
        av = *(const uint4*)ta;
        LOADW(kn);
        COMPUTE(cur);
        STORE(cur ^ 1);
        __syncthreads();
        cur ^= 1;
    }
    COMPUTE(cur);

    // Epilogue: contiguous Ct[u][b][j]; 16 fm-lanes -> 64B runs, no line sharing
    #pragma unroll
    for (int mt = 0; mt < 4; ++mt) {
        const int rbase = b0 + mt * 16 + kq * 4;
        #pragma unroll
        for (int nt = 0; nt < 2; ++nt) {
            const int col = j0 + wn + nt * 16 + fm;
            float* op = Ct + (size_t)u * 262144 + (size_t)rbase * 256 + col;
            op[0]       = acc[mt][nt][0];
            op[256]     = acc[mt][nt][1];
            op[2 * 256] = acc[mt][nt][2];
            op[3 * 256] = acc[mt][nt][3];
        }
    }
}

// ---- assemble3: Ct -> out (contiguous rows via LDS transpose) + out_state
__global__ __launch_bounds__(256) void arma_assemble3(
    const float* __restrict__ state,    // (1024, 32768)
    const float* __restrict__ Ct,       // (32, 1024, 256)
    float* __restrict__ out,            // (1024, 8192)
    float* __restrict__ out_state)      // (1024, 8192, 4)
{
    const int b = blockIdx.x;
    const int t = threadIdx.x;
    __shared__ float L[256 * 33];       // [j][u], pitch 33: conflict-free both ways
    for (int u = 0; u < 32; ++u)
        L[t * 33 + u] = Ct[((size_t)u * 1024 + b) * 256 + t];
    __syncthreads();
    const float* srow = state + (size_t)b * 32768;
    float* orow  = out + (size_t)b * 8192;
    float* osrow = out_state + (size_t)b * 32768;
    for (int w = 0; w < 32; ++w) {
        const int n = w * 256 + t;
        const float o = L[(n >> 5) * 33 + (n & 31)];
        const f32x4 s = *(const f32x4*)(srow + (size_t)n * 4);
        __builtin_nontemporal_store(o, orow + n);
        f32x4 rv = { o, s[0], s[1], s[2] };
        __builtin_nontemporal_store(rv, (f32x4*)(osrow + (size_t)n * 4));
    }
}

// ================= fp32 fallback (any ws size) =====================
#define BM 64
#define BN 64
#define BKF 16
#define LDP 68

__global__ __launch_bounds__(256) void arma_gemm_f32(
    const float* __restrict__ inputs, const float* __restrict__ state,
    const float* __restrict__ kern, const float* __restrict__ rkern,
    float* __restrict__ out)
{
    const int u = blockIdx.z, b0 = blockIdx.x * BM, j0 = blockIdx.y * BN;
    const int tid = threadIdx.x;
    __shared__ float As[BKF][LDP];
    __shared__ float Ws[BKF][LDP];
    const int tx = tid & 15, ty = tid >> 4;
    const int arow = tid >> 2, ak4 = (tid & 3) * 4;
    const int wrow = tid >> 4, wj = (tid & 15) * 4;
    float acc[4][4] = {{0.f}};
    for (int kt = 0; kt < 1024; kt += BKF) {
        const float4 av = *(const float4*)(inputs + (size_t)(b0 + arow) * 1024 + kt + ak4);
        As[ak4 + 0][arow] = av.x; As[ak4 + 1][arow] = av.y;
        As[ak4 + 2][arow] = av.z; As[ak4 + 3][arow] = av.w;
        const int ip = kt + wrow;
        const float4 wv = *(const float4*)(kern + ((size_t)(((ip & 3) * 32 + u) * 256 + (ip >> 2))) * 256 + j0 + wj);
        *(float4*)&Ws[wrow][wj] = wv;
        __syncthreads();
        #pragma unroll
        for (int kk = 0; kk < BKF; ++kk) {
            const float4 a4 = *(const float4*)&As[kk][ty * 4];
            const float4 w4 = *(const float4*)&Ws[kk][tx * 4];
            acc[0][0] += a4.x * w4.x; acc[0][1] += a4.x * w4.y; acc[0][2] += a4.x * w4.z; acc[0][3] += a4.x * w4.w;
            acc[1][0] += a4.y * w4.x; acc[1][1] += a4.y * w4.y; acc[1][2] += a4.y * w4.z; acc[1][3] += a4.y * w4.w;
            acc[2][0] += a4.z * w4.x; acc[2][1] += a4.z * w4.y; acc[2][2] += a4.z * w4.z; acc[2][3] += a4.z * w4.w;
            acc[3][0] += a4.w * w4.x; acc[3][1] += a4.w * w4.y; acc[3][2] += a4.w * w4.z; acc[3][3] += a4.w * w4.w;
        }
        __syncthreads();
    }
    for (int kt = 0; kt < 1024; kt += BKF) {
        const int i = (kt >> 2) + (tid & 3);
        const float4 av = *(const float4*)(state + (size_t)(b0 + arow) * 32768 + (size_t)(i * 32 + u) * 4);
        As[ak4 + 0][arow] = av.x; As[ak4 + 1][arow] = av.y;
        As[ak4 + 2][arow] = av.z; As[ak4 + 3][arow] = av.w;
        const int iq = kt + wrow;
        const float4 wv = *(const float4*)(rkern + ((size_t)(((iq & 3) * 32 + u) * 256 + (iq >> 2))) * 256 + j0 + wj);
        *(float4*)&Ws[wrow][wj] = wv;
        __syncthreads();
        #pragma unroll
        for (int kk = 0; kk < BKF; ++kk) {
            const float4 a4 = *(const float4*)&As[kk][ty * 4];
            const float4 w4 = *(const float4*)&Ws[kk][tx * 4];
            acc[0][0] += a4.x * w4.x; acc[0][1] += a4.x * w4.y; acc[0][2] += a4.x * w4.z; acc[0][3] += a4.x * w4.w;
            acc[1][0] += a4.y * w4.x; acc[1][1] += a4.y * w4.y; acc[1][2] += a4.y * w4.z; acc[1][3] += a4.y * w4.w;
            acc[2][0] += a4.z * w4.x; acc[2][1] += a4.z * w4.y; acc[2][2] += a4.z * w4.z; acc[2][3] += a4.z * w4.w;
            acc[3][0] += a4.w * w4.x; acc[3][1] += a4.w * w4.y; acc[3][2] += a4.w * w4.z; acc[3][3] += a4.w * w4.w;
        }
        __syncthreads();
    }
    const int bb = b0 + ty * 4, jj = j0 + tx * 4;
    #pragma unroll
    for (int r = 0; r < 4; ++r)
        #pragma unroll
        for (int c = 0; c < 4; ++c)
            out[(size_t)(bb + r) * 8192 + (size_t)(jj + c) * 32 + u] = acc[r][c];
}

__global__ __launch_bounds__(256) void arma_assemble2(
    const float* __restrict__ state,
    const float* __restrict__ out,
    float* __restrict__ out_state)
{
    const size_t i = (size_t)blockIdx.x * 256 + threadIdx.x;
    const f32x4 o = *(const f32x4*)(out + i * 4);
    const float* sp = state + i * 16;
    const f32x4 s0 = *(const f32x4*)(sp + 0);
    const f32x4 s1 = *(const f32x4*)(sp + 4);
    const f32x4 s2 = *(const f32x4*)(sp + 8);
    const f32x4 s3 = *(const f32x4*)(sp + 12);
    f32x4 r0 = { o[0], s0[0], s0[1], s0[2] };
    f32x4 r1 = { o[1], s1[0], s1[1], s1[2] };
    f32x4 r2 = { o[2], s2[0], s2[1], s2[2] };
    f32x4 r3 = { o[3], s3[0], s3[1], s3[2] };
    f32x4* dp = (f32x4*)(out_state + i * 16);
    __builtin_nontemporal_store(r0, dp + 0);
    __builtin_nontemporal_store(r1, dp + 1);
    __builtin_nontemporal_store(r2, dp + 2);
    __builtin_nontemporal_store(r3, dp + 3);
}

extern "C" void kernel_launch(void* const* d_in, const int* in_sizes, int n_in,
                              void* d_out, int out_size, void* d_ws, size_t ws_size,
                              hipStream_t stream) {
    const float* inputs = (const float*)d_in[0];
    const float* state  = (const float*)d_in[1];
    const float* kern   = (const float*)d_in[2];
    const float* rkern  = (const float*)d_in[3];

    float* out       = (float*)d_out;
    float* out_state = (float*)d_out + 8388608;

    const size_t WTT_BYTES  = (size_t)32 * 2 * 64 * 128 * 32 * 2;      //  33,554,432
    const size_t ATAR_BYTES = (size_t)16 * 32 * 64 * 32 * 2;           //   2,097,152
    const size_t ATMA_BYTES = (size_t)32 * 16 * 32 * 64 * 32 * 2;      //  67,108,864
    const size_t CT_BYTES   = (size_t)32 * 1024 * 256 * 4;             //  33,554,432
    const size_t R3_BYTES   = WTT_BYTES + ATAR_BYTES + ATMA_BYTES + CT_BYTES; // 136,314,880

    if (ws_size >= R3_BYTES) {
        unsigned short* Wtt   = (unsigned short*)d_ws;
        unsigned short* At_ar = (unsigned short*)((char*)d_ws + WTT_BYTES);
        unsigned short* At_ma = (unsigned short*)((char*)d_ws + WTT_BYTES + ATAR_BYTES);
        float* Ct             = (float*)((char*)d_ws + WTT_BYTES + ATAR_BYTES + ATMA_BYTES);
        prep_all<<<dim3(6656), 256, 0, stream>>>(kern, rkern, inputs, state,
                                                 Wtt, At_ar, At_ma);
        arma_gemm_mfma2ct<<<dim3(1024), 256, 0, stream>>>(At_ar, At_ma, Wtt, Ct);
        arma_assemble3<<<dim3(1024), 256, 0, stream>>>(state, Ct, out, out_state);
    } else {
        arma_gemm_f32<<<dim3(16, 4, 32), 256, 0, stream>>>(inputs, state, kern, rkern, out);
        arma_assemble2<<<8388608 / 4 / 256, 256, 0, stream>>>(state, out, out_state);
    }
}